// Round 1
// baseline (4575.750 us; speedup 1.0000x reference)
//
#include <hip/hip_runtime.h>

typedef _Float16 half2_t __attribute__((ext_vector_type(2)));
typedef _Float16 half8_t __attribute__((ext_vector_type(8)));

union h8pack { half8_t v; half2_t h2[4]; };

constexpr int BATCH = 512;
constexpr int SEQ   = 1000;
constexpr int HID   = 128;
constexpr int GATES = 4 * HID;   // 512
constexpr int TPB   = 1024;      // 2 threads per gate column (k-split)
constexpr int ROWS  = 2;         // batch rows per block -> 256 blocks = 1/CU
constexpr int KHALF = HID / 2;   // 64 k-elements per thread

#if __has_builtin(__builtin_amdgcn_fdot2)
__device__ __forceinline__ float fdot2(half2_t a, half2_t b, float c) {
  return __builtin_amdgcn_fdot2(a, b, c, false);
}
#else
__device__ __forceinline__ float fdot2(half2_t a, half2_t b, float c) {
  return c + (float)a[0] * (float)b[0] + (float)a[1] * (float)b[1];
}
#endif

__device__ __forceinline__ float fast_sigmoid(float x) {
  x = fminf(fmaxf(x, -30.f), 30.f);
  return __fdividef(1.f, 1.f + __expf(-x));
}
__device__ __forceinline__ float fast_tanh(float x) {
  x = fminf(fmaxf(x, -15.f), 15.f);
  float e = __expf(2.f * x);
  return __fdividef(e - 1.f, e + 1.f);
}

// Load 64 f32 -> 32 half2 registers in 16B chunks; fences every 4 chunks keep
// the transient load window small so init doesn't spike register pressure.
__device__ __forceinline__ void load_half_row(const float* __restrict__ src,
                                              half2_t* dst) {
  const float4* p = (const float4*)src;
#pragma unroll
  for (int k = 0; k < KHALF / 4; ++k) {   // 16 float4 loads
    float4 f = p[k];
    dst[2 * k]     = half2_t{(_Float16)f.x, (_Float16)f.y};
    dst[2 * k + 1] = half2_t{(_Float16)f.z, (_Float16)f.w};
    if ((k & 3) == 3) asm volatile("" ::: "memory");
  }
}

__global__ __launch_bounds__(TPB)
void lstm_persist(const float* __restrict__ y,
                  const float* __restrict__ W_ih1,
                  const float* __restrict__ W_hh1,
                  const float* __restrict__ b_ih1,
                  const float* __restrict__ b_hh1,
                  const float* __restrict__ W_ih2,
                  const float* __restrict__ W_hh2,
                  const float* __restrict__ b_ih2,
                  const float* __restrict__ b_hh2,
                  const float* __restrict__ W_lin,
                  const float* __restrict__ b_lin,
                  float* __restrict__ out)
{
  const int tid = threadIdx.x;     // 0..1023
  const int j   = tid >> 1;        // gate column 0..511
  const int kh  = tid & 1;         // which half of the k (hidden) dimension
  const int r0  = blockIdx.x * ROWS;

  __shared__ alignas(16) half8_t h1_sh[ROWS][HID / 8];  // h1 state, f16
  __shared__ alignas(16) half8_t h2_sh[ROWS][HID / 8];  // h2 state, f16
  __shared__ float g1_sh[ROWS][GATES];
  __shared__ float g2_sh[ROWS][GATES];
  __shared__ float x_sh[ROWS][SEQ + 8];                 // staged inputs (+pad)

  // ---- stage x for both rows into LDS (coalesced, one-time) ----
  for (int i = tid; i < ROWS * SEQ; i += TPB) {
    const int r  = (i >= SEQ) ? 1 : 0;
    const int tt = i - r * SEQ;
    x_sh[r][tt] = y[(size_t)(r0 + r) * SEQ + tt];
  }
  // ---- zero the h state ----
  if (tid < 64) {
    half8_t z = {};
    if (tid < 32) ((half8_t*)h1_sh)[tid] = z;
    else          ((half8_t*)h2_sh)[tid - 32] = z;
  }

  // ---- this thread's HALF weight rows, packed f16: 3 x 32 VGPRs ----
  half2_t w1[KHALF / 2], w2[KHALF / 2], w3[KHALF / 2];
  load_half_row(W_hh1 + (size_t)j * HID + kh * KHALF, w1);
  load_half_row(W_ih2 + (size_t)j * HID + kh * KHALF, w2);
  load_half_row(W_hh2 + (size_t)j * HID + kh * KHALF, w3);

  const float wih1  = W_ih1[j];
  const float bias1 = b_ih1[j] + b_hh1[j];
  const float bias2 = b_ih2[j] + b_hh2[j];
  const float wla   = W_lin[tid & 63];
  const float wlb   = W_lin[(tid & 63) + 64];
  const float blin  = b_lin[0];

  float c1v = 0.f;               // layer-1 cell (threads 0..255)
  float c2a = 0.f, c2b = 0.f;    // layer-2 cell (waves 4 and 7, 2 elems each)

  __syncthreads();

  float x0 = x_sh[0][0], x1 = x_sh[1][0];
  float xn0 = 0.f, xn1 = 0.f;

  for (int t = 0; t < SEQ; ++t) {
    // ---------- Phase A: layer-1 raw gate partials (all 1024 threads) ----------
    float a0, a1;
    if (kh == 0) { a0 = fmaf(x0, wih1, bias1); a1 = fmaf(x1, wih1, bias1); }
    else         { a0 = 0.f;                   a1 = 0.f; }
#pragma unroll
    for (int c = 0; c < 8; ++c) {
      h8pack u0, u1;
      u0.v = h1_sh[0][kh * 8 + c];
      u1.v = h1_sh[1][kh * 8 + c];
#pragma unroll
      for (int q = 0; q < 4; ++q) {
        a0 = fdot2(w1[4 * c + q], u0.h2[q], a0);
        a1 = fdot2(w1[4 * c + q], u1.h2[q], a1);
      }
    }
    a0 += __shfl_xor(a0, 1);     // pair (2j, 2j+1) lives in the same wave
    a1 += __shfl_xor(a1, 1);
    if (kh == 0) { g1_sh[0][j] = a0; g1_sh[1][j] = a1; }
    __syncthreads();   // bar1: g1 ready; h1 safe to overwrite

    // ---------- Phase B: layer-1 cell update (threads 0..255 = waves 0..3) ----------
    if (tid < ROWS * HID) {
      const int r = tid >> 7, jj = tid & (HID - 1);
      float gi = g1_sh[r][jj];
      float gf = g1_sh[r][jj + HID];
      float gg = g1_sh[r][jj + 2 * HID];
      float go = g1_sh[r][jj + 3 * HID];
      float iv = fast_sigmoid(gi);
      float fv = fast_sigmoid(gf);
      float gv = fast_tanh(gg);
      float ov = fast_sigmoid(go);
      c1v = fmaf(fv, c1v, iv * gv);
      ((_Float16*)h1_sh)[tid] = (_Float16)(ov * fast_tanh(c1v));  // flat == tid
    }
    __syncthreads();   // bar2: h1 ready

    // ---------- Phase C: layer-2 raw gate partials (all 1024 threads) ----------
    float s0, s1;
    if (kh == 0) { s0 = bias2; s1 = bias2; }
    else         { s0 = 0.f;   s1 = 0.f; }
#pragma unroll
    for (int c = 0; c < 8; ++c) {          // W_ih2 . h1
      h8pack u0, u1;
      u0.v = h1_sh[0][kh * 8 + c];
      u1.v = h1_sh[1][kh * 8 + c];
#pragma unroll
      for (int q = 0; q < 4; ++q) {
        s0 = fdot2(w2[4 * c + q], u0.h2[q], s0);
        s1 = fdot2(w2[4 * c + q], u1.h2[q], s1);
      }
    }
    // prefetch next-step x while the dot stream hides LDS latency
    xn0 = x_sh[0][t + 1];
    xn1 = x_sh[1][t + 1];
#pragma unroll
    for (int c = 0; c < 8; ++c) {          // W_hh2 . h2
      h8pack v0, v1;
      v0.v = h2_sh[0][kh * 8 + c];
      v1.v = h2_sh[1][kh * 8 + c];
#pragma unroll
      for (int q = 0; q < 4; ++q) {
        s0 = fdot2(w3[4 * c + q], v0.h2[q], s0);
        s1 = fdot2(w3[4 * c + q], v1.h2[q], s1);
      }
    }
    s0 += __shfl_xor(s0, 1);
    s1 += __shfl_xor(s1, 1);
    if (kh == 0) { g2_sh[0][j] = s0; g2_sh[1][j] = s1; }
    __syncthreads();   // bar3: g2 ready; h2 safe to overwrite

    // ---------- Phase D: layer-2 cell + output (waves 4 and 7, one row each;
    //            overlaps with the other 14 waves starting Phase A of t+1) ----------
    const int wv = tid >> 6;
    if (wv == 4 || wv == 7) {
      const int r = (wv == 4) ? 0 : 1;
      const int l = tid & 63;              // this thread owns elems l and l+64
      float gia = g2_sh[r][l],       gib = g2_sh[r][l + 64];
      float gfa = g2_sh[r][l + 128], gfb = g2_sh[r][l + 192];
      float gga = g2_sh[r][l + 256], ggb = g2_sh[r][l + 320];
      float goa = g2_sh[r][l + 384], gob = g2_sh[r][l + 448];
      float iva = fast_sigmoid(gia), ivb = fast_sigmoid(gib);
      float fva = fast_sigmoid(gfa), fvb = fast_sigmoid(gfb);
      float gva = fast_tanh(gga),    gvb = fast_tanh(ggb);
      float ova = fast_sigmoid(goa), ovb = fast_sigmoid(gob);
      c2a = fmaf(fva, c2a, iva * gva);
      c2b = fmaf(fvb, c2b, ivb * gvb);
      float ha = ova * fast_tanh(c2a);
      float hb = ovb * fast_tanh(c2b);
      _Float16* hp = (_Float16*)h2_sh;
      hp[r * HID + l]      = (_Float16)ha;
      hp[r * HID + l + 64] = (_Float16)hb;
      float pred = fmaf(ha, wla, hb * wlb);
#pragma unroll
      for (int off = 32; off > 0; off >>= 1)
        pred += __shfl_down(pred, off);
      if (l == 0) out[(size_t)(r0 + r) * SEQ + t] = pred + blin;
    }
    x0 = xn0; x1 = xn1;
    // no barrier: next Phase A touches neither g2_sh nor h2_sh; bar1 of t+1
    // (which waves 4/7 reach only after finishing D) orders everything else.
  }
}

extern "C" void kernel_launch(void* const* d_in, const int* in_sizes, int n_in,
                              void* d_out, int out_size, void* d_ws, size_t ws_size,
                              hipStream_t stream) {
  const float* y     = (const float*)d_in[0];
  const float* W_ih1 = (const float*)d_in[1];
  const float* W_hh1 = (const float*)d_in[2];
  const float* b_ih1 = (const float*)d_in[3];
  const float* b_hh1 = (const float*)d_in[4];
  const float* W_ih2 = (const float*)d_in[5];
  const float* W_hh2 = (const float*)d_in[6];
  const float* b_ih2 = (const float*)d_in[7];
  const float* b_hh2 = (const float*)d_in[8];
  const float* W_lin = (const float*)d_in[9];
  const float* b_lin = (const float*)d_in[10];
  float* out = (float*)d_out;

  lstm_persist<<<BATCH / ROWS, TPB, 0, stream>>>(
      y, W_ih1, W_hh1, b_ih1, b_hh1, W_ih2, W_hh2, b_ih2, b_hh2, W_lin, b_lin, out);
}

// Round 2
// 4280.622 us; speedup vs baseline: 1.0689x; 1.0689x over previous
//
#include <hip/hip_runtime.h>

typedef _Float16 half2_t __attribute__((ext_vector_type(2)));
typedef _Float16 half8_t __attribute__((ext_vector_type(8)));

union h8pack { half8_t v; half2_t h2[4]; };

constexpr int BATCH = 512;
constexpr int SEQ   = 1000;
constexpr int HID   = 128;
constexpr int GATES = 4 * HID;   // 512
constexpr int TPB   = 1024;      // 2 threads per gate column (k-split)
constexpr int ROWS  = 2;         // batch rows per block -> 256 blocks = 1/CU
constexpr int KHALF = HID / 2;   // 64 k-elements per thread

#if __has_builtin(__builtin_amdgcn_fdot2)
__device__ __forceinline__ float fdot2(half2_t a, half2_t b, float c) {
  return __builtin_amdgcn_fdot2(a, b, c, false);
}
#else
__device__ __forceinline__ float fdot2(half2_t a, half2_t b, float c) {
  return c + (float)a[0] * (float)b[0] + (float)a[1] * (float)b[1];
}
#endif

__device__ __forceinline__ float fast_sigmoid(float x) {
  x = fminf(fmaxf(x, -30.f), 30.f);
  return __fdividef(1.f, 1.f + __expf(-x));
}
__device__ __forceinline__ float fast_tanh(float x) {
  x = fminf(fmaxf(x, -15.f), 15.f);
  float e = __expf(2.f * x);
  return __fdividef(e - 1.f, e + 1.f);
}

// Load 64 f32 -> 32 half2 registers in 16B chunks; fences every 4 chunks keep
// the transient load window small so init doesn't raise peak pressure.
__device__ __forceinline__ void load_half_row(const float* __restrict__ src,
                                              half2_t* dst) {
  const float4* p = (const float4*)src;
#pragma unroll
  for (int k = 0; k < KHALF / 4; ++k) {   // 16 float4 loads
    float4 f = p[k];
    dst[2 * k]     = half2_t{(_Float16)f.x, (_Float16)f.y};
    dst[2 * k + 1] = half2_t{(_Float16)f.z, (_Float16)f.w};
    if ((k & 3) == 3) asm volatile("" ::: "memory");
  }
}

// launch_bounds(1024, 4): 4 waves/EU == 1 block/CU -> VGPR cap 128, which the
// ~123-reg peak (96 weight half2 + working set) fits. Without the 2nd arg the
// compiler targeted 2 blocks/CU, capped at 64 VGPRs, and spilled all weights
// (round-1 counters: VGPR=64, WRITE_SIZE=93MB of scratch stores).
__global__ __launch_bounds__(TPB, 4)
void lstm_persist(const float* __restrict__ y,
                  const float* __restrict__ W_ih1,
                  const float* __restrict__ W_hh1,
                  const float* __restrict__ b_ih1,
                  const float* __restrict__ b_hh1,
                  const float* __restrict__ W_ih2,
                  const float* __restrict__ W_hh2,
                  const float* __restrict__ b_ih2,
                  const float* __restrict__ b_hh2,
                  const float* __restrict__ W_lin,
                  const float* __restrict__ b_lin,
                  float* __restrict__ out)
{
  const int tid = threadIdx.x;     // 0..1023
  const int j   = tid >> 1;        // gate column 0..511
  const int kh  = tid & 1;         // which half of the k (hidden) dimension
  const int r0  = blockIdx.x * ROWS;

  __shared__ alignas(16) half8_t h1_sh[ROWS][HID / 8];  // h1 state, f16
  __shared__ alignas(16) half8_t h2_sh[ROWS][HID / 8];  // h2 state, f16
  __shared__ float g1_sh[ROWS][GATES];
  __shared__ float g2_sh[ROWS][GATES];
  __shared__ float x_sh[ROWS][SEQ];                     // staged inputs

  // ---- stage x for both rows into LDS (coalesced, one-time) ----
  for (int i = tid; i < ROWS * SEQ; i += TPB) {
    const int r  = (i >= SEQ) ? 1 : 0;
    const int tt = i - r * SEQ;
    x_sh[r][tt] = y[(size_t)(r0 + r) * SEQ + tt];
  }
  // ---- zero the h state ----
  if (tid < 64) {
    half8_t z = {};
    if (tid < 32) ((half8_t*)h1_sh)[tid] = z;
    else          ((half8_t*)h2_sh)[tid - 32] = z;
  }

  // ---- this thread's HALF weight rows, packed f16: 3 x 32 VGPRs ----
  half2_t w1[KHALF / 2], w2[KHALF / 2], w3[KHALF / 2];
  load_half_row(W_hh1 + (size_t)j * HID + kh * KHALF, w1);
  load_half_row(W_ih2 + (size_t)j * HID + kh * KHALF, w2);
  load_half_row(W_hh2 + (size_t)j * HID + kh * KHALF, w3);

  const float wih1  = W_ih1[j];
  const float bias1 = b_ih1[j] + b_hh1[j];
  const float bias2 = b_ih2[j] + b_hh2[j];
  const float wla   = W_lin[tid & 63];
  const float wlb   = W_lin[(tid & 63) + 64];
  const float blin  = b_lin[0];

  float c1v = 0.f;               // layer-1 cell (threads 0..255)
  float c2a = 0.f, c2b = 0.f;    // layer-2 cell (waves 4 and 7, 2 elems each)

  __syncthreads();

  for (int t = 0; t < SEQ; ++t) {
    // ---------- Phase A: layer-1 raw gate partials (all 1024 threads) ----------
    float a0, a1;
    if (kh == 0) {
      a0 = fmaf(x_sh[0][t], wih1, bias1);
      a1 = fmaf(x_sh[1][t], wih1, bias1);
    } else {
      a0 = 0.f; a1 = 0.f;
    }
#pragma unroll
    for (int c = 0; c < 8; ++c) {
      h8pack u0, u1;
      u0.v = h1_sh[0][kh * 8 + c];
      u1.v = h1_sh[1][kh * 8 + c];
#pragma unroll
      for (int q = 0; q < 4; ++q) {
        a0 = fdot2(w1[4 * c + q], u0.h2[q], a0);
        a1 = fdot2(w1[4 * c + q], u1.h2[q], a1);
      }
    }
    a0 += __shfl_xor(a0, 1);     // pair (2j, 2j+1) lives in the same wave
    a1 += __shfl_xor(a1, 1);
    if (kh == 0) { g1_sh[0][j] = a0; g1_sh[1][j] = a1; }
    __syncthreads();   // bar1: g1 ready; h1 safe to overwrite

    // ---------- Phase B: layer-1 cell update (threads 0..255 = waves 0..3) ----------
    if (tid < ROWS * HID) {
      const int r = tid >> 7, jj = tid & (HID - 1);
      float gi = g1_sh[r][jj];
      float gf = g1_sh[r][jj + HID];
      float gg = g1_sh[r][jj + 2 * HID];
      float go = g1_sh[r][jj + 3 * HID];
      float iv = fast_sigmoid(gi);
      float fv = fast_sigmoid(gf);
      float gv = fast_tanh(gg);
      float ov = fast_sigmoid(go);
      c1v = fmaf(fv, c1v, iv * gv);
      ((_Float16*)h1_sh)[tid] = (_Float16)(ov * fast_tanh(c1v));  // flat == tid
    }
    __syncthreads();   // bar2: h1 ready

    // ---------- Phase C: layer-2 raw gate partials (all 1024 threads) ----------
    float s0, s1;
    if (kh == 0) { s0 = bias2; s1 = bias2; }
    else         { s0 = 0.f;   s1 = 0.f; }
#pragma unroll
    for (int c = 0; c < 8; ++c) {          // W_ih2 . h1
      h8pack u0, u1;
      u0.v = h1_sh[0][kh * 8 + c];
      u1.v = h1_sh[1][kh * 8 + c];
#pragma unroll
      for (int q = 0; q < 4; ++q) {
        s0 = fdot2(w2[4 * c + q], u0.h2[q], s0);
        s1 = fdot2(w2[4 * c + q], u1.h2[q], s1);
      }
    }
#pragma unroll
    for (int c = 0; c < 8; ++c) {          // W_hh2 . h2
      h8pack v0, v1;
      v0.v = h2_sh[0][kh * 8 + c];
      v1.v = h2_sh[1][kh * 8 + c];
#pragma unroll
      for (int q = 0; q < 4; ++q) {
        s0 = fdot2(w3[4 * c + q], v0.h2[q], s0);
        s1 = fdot2(w3[4 * c + q], v1.h2[q], s1);
      }
    }
    s0 += __shfl_xor(s0, 1);
    s1 += __shfl_xor(s1, 1);
    if (kh == 0) { g2_sh[0][j] = s0; g2_sh[1][j] = s1; }
    __syncthreads();   // bar3: g2 ready; h2 safe to overwrite

    // ---------- Phase D: layer-2 cell + output (waves 4 and 7, one row each;
    //            overlaps with the other 14 waves starting Phase A of t+1) ----------
    const int wv = tid >> 6;
    if (wv == 4 || wv == 7) {
      const int r = (wv == 4) ? 0 : 1;
      const int l = tid & 63;              // this thread owns elems l and l+64
      float gia = g2_sh[r][l],       gib = g2_sh[r][l + 64];
      float gfa = g2_sh[r][l + 128], gfb = g2_sh[r][l + 192];
      float gga = g2_sh[r][l + 256], ggb = g2_sh[r][l + 320];
      float goa = g2_sh[r][l + 384], gob = g2_sh[r][l + 448];
      float iva = fast_sigmoid(gia), ivb = fast_sigmoid(gib);
      float fva = fast_sigmoid(gfa), fvb = fast_sigmoid(gfb);
      float gva = fast_tanh(gga),    gvb = fast_tanh(ggb);
      float ova = fast_sigmoid(goa), ovb = fast_sigmoid(gob);
      c2a = fmaf(fva, c2a, iva * gva);
      c2b = fmaf(fvb, c2b, ivb * gvb);
      float ha = ova * fast_tanh(c2a);
      float hb = ovb * fast_tanh(c2b);
      _Float16* hp = (_Float16*)h2_sh;
      hp[r * HID + l]      = (_Float16)ha;
      hp[r * HID + l + 64] = (_Float16)hb;
      float pred = fmaf(ha, wla, hb * wlb);
#pragma unroll
      for (int off = 32; off > 0; off >>= 1)
        pred += __shfl_down(pred, off);
      if (l == 0) out[(size_t)(r0 + r) * SEQ + t] = pred + blin;
    }
    // no barrier: next Phase A touches neither g2_sh nor h2_sh; bar1 of t+1
    // (which waves 4/7 reach only after finishing D) orders everything else.
  }
}

extern "C" void kernel_launch(void* const* d_in, const int* in_sizes, int n_in,
                              void* d_out, int out_size, void* d_ws, size_t ws_size,
                              hipStream_t stream) {
  const float* y     = (const float*)d_in[0];
  const float* W_ih1 = (const float*)d_in[1];
  const float* W_hh1 = (const float*)d_in[2];
  const float* b_ih1 = (const float*)d_in[3];
  const float* b_hh1 = (const float*)d_in[4];
  const float* W_ih2 = (const float*)d_in[5];
  const float* W_hh2 = (const float*)d_in[6];
  const float* b_ih2 = (const float*)d_in[7];
  const float* b_hh2 = (const float*)d_in[8];
  const float* W_lin = (const float*)d_in[9];
  const float* b_lin = (const float*)d_in[10];
  float* out = (float*)d_out;

  lstm_persist<<<BATCH / ROWS, TPB, 0, stream>>>(
      y, W_ih1, W_hh1, b_ih1, b_hh1, W_ih2, W_hh2, b_ih2, b_hh2, W_lin, b_lin, out);
}